// Round 2
// 59.207 us; speedup vs baseline: 1.0206x; 1.0206x over previous
//
#include <hip/hip_runtime.h>

// Fused:  t4[o,n,m,i] = sum_{j,k} a[o,j,n,m+k-3] * W1[j,k,i]
//         out[0, o*48+p, (n+1)%56, m] = sum_i t4[o,n,m,i] * W0[p,i]
//
// v3: grid = 224 (2 blocks per (o,n) source row; each writes a 24-p half),
// 256 threads. Changes vs v2:
//  - input row staged as aligned float4 (pad-4 layout: data at sA[j][4..59])
//  - W1 repacked to [84][12] so phase 1 reads weights as b128+b128+b32
//    (84 LDS instrs/wave instead of 210)
//  - phase 1b reduced with float4 (126 ops, single shot)
//  - phase 2 halved per block (24 p's) -> 336 float4 stores

__global__ __launch_bounds__(256) void fused_shiftconv_v3(
    const float* __restrict__ x,    // (24,56,56) viewed as a(2,12,56,56)
    const float* __restrict__ W0,   // (48,9)
    const float* __restrict__ W1,   // (12,7,9)
    float* __restrict__ out)        // (96,56,56)
{
    __shared__ __align__(16) float sA[12][64];      // data at [4..59], zero pads
    __shared__ __align__(16) float sW1p[84][12];    // [j*7+k][i], 12-float stride
    __shared__ __align__(16) float sW0[432];        // [p*9 + i]
    __shared__ __align__(16) float sPart[4][9][60]; // per-wave j-partials
    __shared__ __align__(16) float sT4t[9][60];     // t4 transposed: [i][m]

    const int tid = threadIdx.x;
    const int b   = blockIdx.x;
    const int h   = b & 1;          // which 24-p half this block writes
    const int on  = b >> 1;
    const int o   = on / 56;
    const int n   = on % 56;

    // --- stage input row: 12 rows x 14 float4, all 16B-aligned ---
    if (tid < 168) {
        const int j = tid / 14, q = tid % 14;
        *(float4*)&sA[j][4 + 4*q] =
            *(const float4*)(x + (((o*12 + j)*56 + n)*56 + 4*q));
    } else if (tid < 192) {
        const int t = tid - 168;    // zero the 4-float pads on both ends
        *(float4*)&sA[t >> 1][(t & 1) ? 60 : 0] =
            make_float4(0.f, 0.f, 0.f, 0.f);
    }
    // --- stage W1 repacked: global [jk*9+i] -> LDS [jk*12+i] ---
    if (tid < 189) {
        const float4 v = ((const float4*)W1)[tid];
        const float vv[4] = {v.x, v.y, v.z, v.w};
#pragma unroll
        for (int c = 0; c < 4; ++c) {
            const int e  = tid*4 + c;
            const int jk = e / 9;
            ((float*)sW1p)[jk*12 + (e - jk*9)] = vv[c];
        }
    }
    // --- stage W0 (432 floats = 108 float4) ---
    if (tid < 108) ((float4*)sW0)[tid] = ((const float4*)W0)[tid];
    __syncthreads();

    // --- phase 1: wave w accumulates j = 3w..3w+2 (lanes 0..55 = m) ---
    {
        const int wave = tid >> 6, lane = tid & 63;
        if (lane < 56) {
            const int m = lane;
            float acc[9];
#pragma unroll
            for (int i = 0; i < 9; ++i) acc[i] = 0.0f;
#pragma unroll
            for (int jj = 0; jj < 3; ++jj) {
                const int j = wave*3 + jj;
#pragma unroll
                for (int k = 0; k < 7; ++k) {
                    const float v  = sA[j][m + k + 1];        // pad-4 layout
                    const float* wp = &sW1p[j*7 + k][0];      // 48B-aligned
                    const float4 wa = *(const float4*)(wp);
                    const float4 wb = *(const float4*)(wp + 4);
                    const float  w8 = wp[8];
                    acc[0] += v*wa.x; acc[1] += v*wa.y;
                    acc[2] += v*wa.z; acc[3] += v*wa.w;
                    acc[4] += v*wb.x; acc[5] += v*wb.y;
                    acc[6] += v*wb.z; acc[7] += v*wb.w;
                    acc[8] += v*w8;
                }
            }
#pragma unroll
            for (int i = 0; i < 9; ++i) sPart[wave][i][m] = acc[i];
        }
    }
    __syncthreads();

    // --- phase 1b: reduce 4 partials into transposed t4 (float4, 1 shot) ---
    if (tid < 126) {
        const int i = tid / 14, m0 = (tid % 14) * 4;
        const float4 s0 = *(const float4*)&sPart[0][i][m0];
        const float4 s1 = *(const float4*)&sPart[1][i][m0];
        const float4 s2 = *(const float4*)&sPart[2][i][m0];
        const float4 s3 = *(const float4*)&sPart[3][i][m0];
        float4 r;
        r.x = (s0.x + s1.x) + (s2.x + s3.x);
        r.y = (s0.y + s1.y) + (s2.y + s3.y);
        r.z = (s0.z + s1.z) + (s2.z + s3.z);
        r.w = (s0.w + s1.w) + (s2.w + s3.w);
        *(float4*)&sT4t[i][m0] = r;
    }
    __syncthreads();

    // --- phase 2: 24x56 outputs as 336 float4 (roll +1 along n) ---
    const int n_out = (n + 1) % 56;
    for (int v4 = tid; v4 < 336; v4 += 256) {
        const int pl = v4 / 14;
        const int m0 = (v4 % 14) * 4;
        const int p  = h*24 + pl;
        const float* w = &sW0[p * 9];
        float4 acc = make_float4(0.0f, 0.0f, 0.0f, 0.0f);
#pragma unroll
        for (int i = 0; i < 9; ++i) {
            const float4 t = *(const float4*)&sT4t[i][m0];   // ds_read_b128
            const float wi = w[i];
            acc.x += wi*t.x; acc.y += wi*t.y;
            acc.z += wi*t.z; acc.w += wi*t.w;
        }
        *(float4*)&out[((o*48 + p)*56 + n_out)*56 + m0] = acc;
    }
}

extern "C" void kernel_launch(void* const* d_in, const int* in_sizes, int n_in,
                              void* d_out, int out_size, void* d_ws, size_t ws_size,
                              hipStream_t stream) {
    const float* x  = (const float*)d_in[0];
    const float* W0 = (const float*)d_in[1];
    const float* W1 = (const float*)d_in[2];
    float* out = (float*)d_out;

    fused_shiftconv_v3<<<dim3(224), dim3(256), 0, stream>>>(x, W0, W1, out);
}